// Round 1
// baseline (1124.677 us; speedup 1.0000x reference)
//
#include <hip/hip_runtime.h>
#include <math.h>

// Problem constants (from reference)
constexpr int NN  = 100000;   // nodes
constexpr int EE  = 1600000;  // edges
constexpr int IND = 128;      // input dim
constexpr int HID = 64;       // hidden dim

// ---------------- degree / norm ----------------

__global__ __launch_bounds__(256) void k_init_deg(float* __restrict__ deg) {
    int i = blockIdx.x * 256 + threadIdx.x;
    if (i < NN) deg[i] = 1.0f;   // self-loop contributes 1
}

__global__ __launch_bounds__(256) void k_count(const int* __restrict__ col, float* __restrict__ deg) {
    int i = blockIdx.x * 256 + threadIdx.x;
    if (i < EE) atomicAdd(&deg[col[i]], 1.0f);   // exact: counts << 2^24
}

__global__ __launch_bounds__(256) void k_dinv(float* __restrict__ deg) {
    int i = blockIdx.x * 256 + threadIdx.x;
    if (i < NN) deg[i] = rsqrtf(deg[i]);         // deg >= 1 always
}

// ---------------- fc: h = x @ fc_w + fc_b  (128 -> 64) ----------------
// one wave per row; lane = output column; x-row held in 2 regs, broadcast via readlane

__global__ __launch_bounds__(256) void k_fc(const float* __restrict__ x, const float* __restrict__ w,
                                            const float* __restrict__ b, float* __restrict__ h) {
    __shared__ float wl[IND * HID];   // 32 KB
    for (int i = threadIdx.x; i < IND * HID; i += 256) wl[i] = w[i];
    __syncthreads();
    int lane = threadIdx.x & 63;
    int slot = threadIdx.x >> 6;      // 4 waves per block
    float bj = b[lane];
    for (int r = blockIdx.x * 4 + slot; r < NN; r += gridDim.x * 4) {
        float v0 = x[r * IND + lane];
        float v1 = x[r * IND + 64 + lane];
        float acc = bj;
        #pragma unroll
        for (int k = 0; k < 64; ++k) {
            acc += __shfl(v0, k, 64) * wl[k * HID + lane];
            acc += __shfl(v1, k, 64) * wl[(64 + k) * HID + lane];
        }
        h[r * HID + lane] = acc;
    }
}

// ---------------- conv matmul: m = hin @ W; agg = m * dinv^2 (self-loop init) ----
// NOTE: agg may alias hin (each row is read and written by exactly one wave,
// read-before-write within the wave) -> no __restrict__ on hin/agg.

__global__ __launch_bounds__(256) void k_mm(const float* hin, const float* __restrict__ w,
                                            const float* __restrict__ dinv,
                                            float* __restrict__ m, float* agg) {
    __shared__ float wl[HID * HID];   // 16 KB
    for (int i = threadIdx.x; i < HID * HID; i += 256) wl[i] = w[i];
    __syncthreads();
    int lane = threadIdx.x & 63;
    int slot = threadIdx.x >> 6;
    for (int r = blockIdx.x * 4 + slot; r < NN; r += gridDim.x * 4) {
        float v = hin[r * HID + lane];
        float acc = 0.f;
        #pragma unroll
        for (int k = 0; k < 64; ++k)
            acc += __shfl(v, k, 64) * wl[k * HID + lane];
        float di = dinv[r];
        m[r * HID + lane] = acc;
        agg[r * HID + lane] = acc * di * di;   // self-loop: dinv[i]^2 * m[i]
    }
}

// ---------------- scatter: agg[col] += m[row] * dinv[row]*dinv[col] ----------------
// one wave per edge; lane = feature; coalesced gather + 64 consecutive atomics

__global__ __launch_bounds__(256) void k_scatter(const int* __restrict__ row, const int* __restrict__ col,
                                                 const float* __restrict__ dinv, const float* __restrict__ m,
                                                 float* __restrict__ agg) {
    int lane = threadIdx.x & 63;
    int wid  = (blockIdx.x * blockDim.x + threadIdx.x) >> 6;
    int nw   = (gridDim.x * blockDim.x) >> 6;
    for (int e = wid; e < EE; e += nw) {
        int r = row[e], c = col[e];
        float coeff = dinv[r] * dinv[c];
        float v = m[r * HID + lane] * coeff;
        atomicAdd(&agg[c * HID + lane], v);
    }
}

// ---------------- bias + relu (in place OK: pure elementwise) ----------------

__global__ __launch_bounds__(256) void k_bias_relu(const float* agg, const float* __restrict__ b,
                                                   float* hout) {
    int stride = gridDim.x * 256;
    for (int i = blockIdx.x * 256 + threadIdx.x; i < NN * HID; i += stride) {
        float v = agg[i] + b[i & 63];
        hout[i] = v > 0.f ? v : 0.f;
    }
}

// ---------------- node scores + per-node edge partials ----------------

__global__ __launch_bounds__(256) void k_node(const float* __restrict__ h, const float* __restrict__ nw,
                                              const float* __restrict__ nb, const float* __restrict__ ew,
                                              float* __restrict__ out_node, float* __restrict__ ssrc,
                                              float* __restrict__ sdst) {
    int lane = threadIdx.x & 63;
    int wid  = (blockIdx.x * blockDim.x + threadIdx.x) >> 6;
    int nwv  = (gridDim.x * blockDim.x) >> 6;
    float w0 = nw[lane], w1 = ew[lane], w2 = ew[64 + lane];
    float nb0 = nb[0];
    for (int i = wid; i < NN; i += nwv) {
        float v = h[i * HID + lane];
        float a = v * w0, s1 = v * w1, s2 = v * w2;
        #pragma unroll
        for (int off = 32; off; off >>= 1) {
            a  += __shfl_xor(a,  off, 64);
            s1 += __shfl_xor(s1, off, 64);
            s2 += __shfl_xor(s2, off, 64);
        }
        if (lane == 0) {
            out_node[i] = 1.f / (1.f + expf(-(a + nb0)));
            ssrc[i] = s1;
            sdst[i] = s2;
        }
    }
}

// ---------------- edge scores ----------------

__global__ __launch_bounds__(256) void k_edge(const int* __restrict__ row, const int* __restrict__ col,
                                              const float* __restrict__ ssrc, const float* __restrict__ sdst,
                                              const float* __restrict__ eb, float* __restrict__ out_edge) {
    int stride = gridDim.x * 256;
    float eb0 = eb[0];
    for (int i = blockIdx.x * 256 + threadIdx.x; i < EE; i += stride) {
        float z = ssrc[row[i]] + sdst[col[i]] + eb0;
        out_edge[i] = 1.f / (1.f + expf(-z));
    }
}

extern "C" void kernel_launch(void* const* d_in, const int* in_sizes, int n_in,
                              void* d_out, int out_size, void* d_ws, size_t ws_size,
                              hipStream_t stream) {
    const float* x    = (const float*)d_in[0];
    const int*   ei   = (const int*)d_in[1];
    const float* fc_w = (const float*)d_in[2];
    const float* fc_b = (const float*)d_in[3];
    const float* c1w  = (const float*)d_in[4];
    const float* c1b  = (const float*)d_in[5];
    const float* c2w  = (const float*)d_in[6];
    const float* c2b  = (const float*)d_in[7];
    const float* nw   = (const float*)d_in[8];
    const float* nb   = (const float*)d_in[9];
    const float* ew   = (const float*)d_in[10];
    const float* eb   = (const float*)d_in[11];
    const int* row = ei;        // edge_index[0]
    const int* col = ei + EE;   // edge_index[1]

    // workspace layout (floats): dinv[N] ssrc[N] sdst[N] | A[N*HID] B[N*HID]
    float* ws   = (float*)d_ws;
    float* dinv = ws;
    float* ssrc = ws + 102400;
    float* sdst = ws + 2 * 102400;
    float* A    = ws + 3 * 102400;   // h / agg (aliased, safe per-row)
    float* B    = A + (size_t)NN * HID;  // m

    float* out_edge = (float*)d_out;
    float* out_node = out_edge + EE;

    const int nb256N = (NN + 255) / 256;
    const int nb256E = (EE + 255) / 256;

    // degree norm
    k_init_deg<<<nb256N, 256, 0, stream>>>(dinv);
    k_count  <<<nb256E, 256, 0, stream>>>(col, dinv);
    k_dinv   <<<nb256N, 256, 0, stream>>>(dinv);

    // fc
    k_fc<<<2048, 256, 0, stream>>>(x, fc_w, fc_b, A);

    // conv1: m = A@W -> B; agg(self-loop) -> A; scatter B into A; relu in place
    k_mm     <<<2048, 256, 0, stream>>>(A, c1w, dinv, B, A);
    k_scatter<<<4096, 256, 0, stream>>>(row, col, dinv, B, A);
    k_bias_relu<<<2048, 256, 0, stream>>>(A, c1b, A);

    // conv2
    k_mm     <<<2048, 256, 0, stream>>>(A, c2w, dinv, B, A);
    k_scatter<<<4096, 256, 0, stream>>>(row, col, dinv, B, A);
    k_bias_relu<<<2048, 256, 0, stream>>>(A, c2b, A);

    // scores
    k_node<<<2048, 256, 0, stream>>>(A, nw, nb, ew, out_node, ssrc, sdst);
    k_edge<<<2048, 256, 0, stream>>>(row, col, ssrc, sdst, eb, out_edge);
}

// Round 2
// 660.261 us; speedup vs baseline: 1.7034x; 1.7034x over previous
//
#include <hip/hip_runtime.h>
#include <math.h>

// Problem constants (from reference)
constexpr int NN  = 100000;   // nodes
constexpr int EE  = 1600000;  // edges
constexpr int IND = 128;      // input dim
constexpr int HID = 64;       // hidden dim
constexpr int NB_SCAN = (NN + 255) / 256;   // 391 scan blocks

// ---------------- zero / histogram / scan / permute (CSR build by col) ------

__global__ __launch_bounds__(256) void k_zero(int* __restrict__ p, int n) {
    int i = blockIdx.x * 256 + threadIdx.x;
    if (i < n) p[i] = 0;
}

__global__ __launch_bounds__(256) void k_hist(const int* __restrict__ col, int* __restrict__ cnt) {
    int e = blockIdx.x * 256 + threadIdx.x;
    if (e < EE) atomicAdd(&cnt[col[e]], 1);
}

// Phase A: per-block exclusive scan of cnt -> base (partial), block totals -> bsum
__global__ __launch_bounds__(256) void k_scanA(const int* __restrict__ cnt, int* __restrict__ base,
                                               int* __restrict__ bsum) {
    __shared__ int tmp[256];
    int t = threadIdx.x, i = blockIdx.x * 256 + t;
    int v = (i < NN) ? cnt[i] : 0;
    tmp[t] = v;
    __syncthreads();
    #pragma unroll
    for (int off = 1; off < 256; off <<= 1) {
        int add = (t >= off) ? tmp[t - off] : 0;
        __syncthreads();
        tmp[t] += add;
        __syncthreads();
    }
    if (i < NN) base[i] = tmp[t] - v;          // exclusive within block
    if (t == 255) bsum[blockIdx.x] = tmp[255]; // block total
}

// Phase B: single-block exclusive scan of the 391 block totals (512 threads)
__global__ __launch_bounds__(512) void k_scanB(int* __restrict__ bsum) {
    __shared__ int tmp[512];
    int t = threadIdx.x;
    int v = (t < NB_SCAN) ? bsum[t] : 0;
    tmp[t] = v;
    __syncthreads();
    #pragma unroll
    for (int off = 1; off < 512; off <<= 1) {
        int add = (t >= off) ? tmp[t - off] : 0;
        __syncthreads();
        tmp[t] += add;
        __syncthreads();
    }
    if (t < NB_SCAN) bsum[t] = tmp[t] - v;     // exclusive
}

// Phase C: base += block offset; cursor = base; dinv = rsqrt(cnt+1)
__global__ __launch_bounds__(256) void k_finalize(int* __restrict__ base, const int* __restrict__ bsum,
                                                  const int* __restrict__ cnt, int* __restrict__ cursor,
                                                  float* __restrict__ dinv) {
    int i = blockIdx.x * 256 + threadIdx.x;
    if (i < NN) {
        int v = base[i] + bsum[blockIdx.x];
        base[i] = v;
        cursor[i] = v;
        dinv[i] = rsqrtf((float)(cnt[i] + 1));   // +1 = self-loop
    }
}

// Scatter edge rows into col-sorted order
__global__ __launch_bounds__(256) void k_permute(const int* __restrict__ row, const int* __restrict__ col,
                                                 int* __restrict__ cursor, int* __restrict__ prow) {
    int e = blockIdx.x * 256 + threadIdx.x;
    if (e < EE) {
        int c = col[e];
        int p = atomicAdd(&cursor[c], 1);
        prow[p] = row[e];
    }
}

// ---------------- fc: h = x @ fc_w + fc_b  (128 -> 64) ----------------

__global__ __launch_bounds__(256) void k_fc(const float* __restrict__ x, const float* __restrict__ w,
                                            const float* __restrict__ b, float* __restrict__ h) {
    __shared__ float wl[IND * HID];   // 32 KB
    for (int i = threadIdx.x; i < IND * HID; i += 256) wl[i] = w[i];
    __syncthreads();
    int lane = threadIdx.x & 63;
    int slot = threadIdx.x >> 6;      // 4 waves per block
    float bj = b[lane];
    for (int r = blockIdx.x * 4 + slot; r < NN; r += gridDim.x * 4) {
        float v0 = x[r * IND + lane];
        float v1 = x[r * IND + 64 + lane];
        float acc = bj;
        #pragma unroll
        for (int k = 0; k < 64; ++k) {
            acc += __shfl(v0, k, 64) * wl[k * HID + lane];
            acc += __shfl(v1, k, 64) * wl[(64 + k) * HID + lane];
        }
        h[r * HID + lane] = acc;
    }
}

// ---------------- conv matmul: md = (hin @ W) * dinv[row] ----------------

__global__ __launch_bounds__(256) void k_mm(const float* __restrict__ hin, const float* __restrict__ w,
                                            const float* __restrict__ dinv, float* __restrict__ md) {
    __shared__ float wl[HID * HID];   // 16 KB
    for (int i = threadIdx.x; i < HID * HID; i += 256) wl[i] = w[i];
    __syncthreads();
    int lane = threadIdx.x & 63;
    int slot = threadIdx.x >> 6;
    for (int r = blockIdx.x * 4 + slot; r < NN; r += gridDim.x * 4) {
        float v = hin[r * HID + lane];
        float acc = 0.f;
        #pragma unroll
        for (int k = 0; k < 64; ++k)
            acc += __shfl(v, k, 64) * wl[k * HID + lane];
        md[r * HID + lane] = acc * dinv[r];
    }
}

// ---------------- gather conv: hout = relu(dinv[i]*(sum md[r] + md[i]) + b) --
// wave per node; lane = feature; CSR pull — no atomics.

__global__ __launch_bounds__(256) void k_gather(const float* __restrict__ md, const int* __restrict__ prow,
                                                const int* __restrict__ base, const int* __restrict__ cnt,
                                                const float* __restrict__ dinv, const float* __restrict__ b,
                                                float* __restrict__ hout) {
    int lane = threadIdx.x & 63;
    int wid  = (blockIdx.x * blockDim.x + threadIdx.x) >> 6;
    int nwv  = (gridDim.x * blockDim.x) >> 6;
    float bj = b[lane];
    for (int i = wid; i < NN; i += nwv) {
        int s = base[i], n = cnt[i];
        float acc = md[i * HID + lane];      // self-loop term (md[i] = dinv[i]*m[i])
        int e = 0;
        for (; e + 4 <= n; e += 4) {         // unroll x4: 4 gathers in flight
            int r0 = prow[s + e],     r1 = prow[s + e + 1];
            int r2 = prow[s + e + 2], r3 = prow[s + e + 3];
            float v0 = md[r0 * HID + lane], v1 = md[r1 * HID + lane];
            float v2 = md[r2 * HID + lane], v3 = md[r3 * HID + lane];
            acc += (v0 + v1) + (v2 + v3);
        }
        for (; e < n; ++e) acc += md[prow[s + e] * HID + lane];
        float v = dinv[i] * acc + bj;
        hout[i * HID + lane] = v > 0.f ? v : 0.f;
    }
}

// ---------------- node scores + per-node edge partials ----------------

__global__ __launch_bounds__(256) void k_node(const float* __restrict__ h, const float* __restrict__ nw,
                                              const float* __restrict__ nb, const float* __restrict__ ew,
                                              float* __restrict__ out_node, float* __restrict__ ssrc,
                                              float* __restrict__ sdst) {
    int lane = threadIdx.x & 63;
    int wid  = (blockIdx.x * blockDim.x + threadIdx.x) >> 6;
    int nwv  = (gridDim.x * blockDim.x) >> 6;
    float w0 = nw[lane], w1 = ew[lane], w2 = ew[64 + lane];
    float nb0 = nb[0];
    for (int i = wid; i < NN; i += nwv) {
        float v = h[i * HID + lane];
        float a = v * w0, s1 = v * w1, s2 = v * w2;
        #pragma unroll
        for (int off = 32; off; off >>= 1) {
            a  += __shfl_xor(a,  off, 64);
            s1 += __shfl_xor(s1, off, 64);
            s2 += __shfl_xor(s2, off, 64);
        }
        if (lane == 0) {
            out_node[i] = 1.f / (1.f + expf(-(a + nb0)));
            ssrc[i] = s1;
            sdst[i] = s2;
        }
    }
}

// ---------------- edge scores ----------------

__global__ __launch_bounds__(256) void k_edge(const int* __restrict__ row, const int* __restrict__ col,
                                              const float* __restrict__ ssrc, const float* __restrict__ sdst,
                                              const float* __restrict__ eb, float* __restrict__ out_edge) {
    int stride = gridDim.x * 256;
    float eb0 = eb[0];
    for (int i = blockIdx.x * 256 + threadIdx.x; i < EE; i += stride) {
        float z = ssrc[row[i]] + sdst[col[i]] + eb0;
        out_edge[i] = 1.f / (1.f + expf(-z));
    }
}

extern "C" void kernel_launch(void* const* d_in, const int* in_sizes, int n_in,
                              void* d_out, int out_size, void* d_ws, size_t ws_size,
                              hipStream_t stream) {
    const float* x    = (const float*)d_in[0];
    const int*   ei   = (const int*)d_in[1];
    const float* fc_w = (const float*)d_in[2];
    const float* fc_b = (const float*)d_in[3];
    const float* c1w  = (const float*)d_in[4];
    const float* c1b  = (const float*)d_in[5];
    const float* c2w  = (const float*)d_in[6];
    const float* c2b  = (const float*)d_in[7];
    const float* nw   = (const float*)d_in[8];
    const float* nb   = (const float*)d_in[9];
    const float* ew   = (const float*)d_in[10];
    const float* eb   = (const float*)d_in[11];
    const int* row = ei;        // edge_index[0]
    const int* col = ei + EE;   // edge_index[1]

    // workspace layout (all 4-byte elems, node arrays padded to 102400)
    constexpr int NP = 102400;
    float* ws     = (float*)d_ws;
    float* dinv   = ws;
    float* ssrc   = ws + NP;
    float* sdst   = ws + 2 * NP;
    int*   cnt    = (int*)(ws + 3 * NP);
    int*   base   = (int*)(ws + 4 * NP);
    int*   cursor = (int*)(ws + 5 * NP);
    int*   bsum   = (int*)(ws + 6 * NP);          // 512 ints
    int*   prow   = (int*)(ws + 6 * NP + 512);    // EE ints
    float* A      = ws + 6 * NP + 512 + EE;       // h  [N*HID]
    float* B      = A + (size_t)NN * HID;         // md [N*HID]

    float* out_edge = (float*)d_out;
    float* out_node = out_edge + EE;

    const int nbN = (NN + 255) / 256;   // 391
    const int nbE = (EE + 255) / 256;   // 6250

    // ---- CSR build (once, reused by both convs) + degree norm ----
    k_zero    <<<nbN, 256, 0, stream>>>(cnt, NN);
    k_hist    <<<nbE, 256, 0, stream>>>(col, cnt);
    k_scanA   <<<NB_SCAN, 256, 0, stream>>>(cnt, base, bsum);
    k_scanB   <<<1, 512, 0, stream>>>(bsum);
    k_finalize<<<NB_SCAN, 256, 0, stream>>>(base, bsum, cnt, cursor, dinv);
    k_permute <<<nbE, 256, 0, stream>>>(row, col, cursor, prow);

    // ---- fc ----
    k_fc<<<2048, 256, 0, stream>>>(x, fc_w, fc_b, A);

    // ---- conv1 ----
    k_mm    <<<2048, 256, 0, stream>>>(A, c1w, dinv, B);
    k_gather<<<2048, 256, 0, stream>>>(B, prow, base, cnt, dinv, c1b, A);

    // ---- conv2 ----
    k_mm    <<<2048, 256, 0, stream>>>(A, c2w, dinv, B);
    k_gather<<<2048, 256, 0, stream>>>(B, prow, base, cnt, dinv, c2b, A);

    // ---- scores ----
    k_node<<<2048, 256, 0, stream>>>(A, nw, nb, ew, out_node, ssrc, sdst);
    k_edge<<<2048, 256, 0, stream>>>(row, col, ssrc, sdst, eb, out_edge);
}

// Round 3
// 548.208 us; speedup vs baseline: 2.0516x; 1.2044x over previous
//
#include <hip/hip_runtime.h>
#include <math.h>

// Problem constants (from reference)
constexpr int NN  = 100000;   // nodes
constexpr int EE  = 1600000;  // edges
constexpr int IND = 128;      // input dim
constexpr int HID = 64;       // hidden dim
constexpr int NB_SCAN = (NN + 255) / 256;   // 391 scan blocks

// ---------------- zero / histogram / scan / permute (CSR build by col) ------

__global__ __launch_bounds__(256) void k_zero(int* __restrict__ p, int n) {
    int i = blockIdx.x * 256 + threadIdx.x;
    if (i < n) p[i] = 0;
}

__global__ __launch_bounds__(256) void k_hist(const int* __restrict__ col, int* __restrict__ cnt) {
    int e = blockIdx.x * 256 + threadIdx.x;
    if (e < EE) atomicAdd(&cnt[col[e]], 1);
}

__global__ __launch_bounds__(256) void k_scanA(const int* __restrict__ cnt, int* __restrict__ base,
                                               int* __restrict__ bsum) {
    __shared__ int tmp[256];
    int t = threadIdx.x, i = blockIdx.x * 256 + t;
    int v = (i < NN) ? cnt[i] : 0;
    tmp[t] = v;
    __syncthreads();
    #pragma unroll
    for (int off = 1; off < 256; off <<= 1) {
        int add = (t >= off) ? tmp[t - off] : 0;
        __syncthreads();
        tmp[t] += add;
        __syncthreads();
    }
    if (i < NN) base[i] = tmp[t] - v;
    if (t == 255) bsum[blockIdx.x] = tmp[255];
}

__global__ __launch_bounds__(512) void k_scanB(int* __restrict__ bsum) {
    __shared__ int tmp[512];
    int t = threadIdx.x;
    int v = (t < NB_SCAN) ? bsum[t] : 0;
    tmp[t] = v;
    __syncthreads();
    #pragma unroll
    for (int off = 1; off < 512; off <<= 1) {
        int add = (t >= off) ? tmp[t - off] : 0;
        __syncthreads();
        tmp[t] += add;
        __syncthreads();
    }
    if (t < NB_SCAN) bsum[t] = tmp[t] - v;
}

__global__ __launch_bounds__(256) void k_finalize(int* __restrict__ base, const int* __restrict__ bsum,
                                                  const int* __restrict__ cnt, int* __restrict__ cursor,
                                                  float* __restrict__ dinv) {
    int i = blockIdx.x * 256 + threadIdx.x;
    if (i < NN) {
        int v = base[i] + bsum[blockIdx.x];
        base[i] = v;
        cursor[i] = v;
        dinv[i] = rsqrtf((float)(cnt[i] + 1));   // +1 = self-loop
    }
}

__global__ __launch_bounds__(256) void k_permute(const int* __restrict__ row, const int* __restrict__ col,
                                                 int* __restrict__ cursor, int* __restrict__ prow) {
    int e = blockIdx.x * 256 + threadIdx.x;
    if (e < EE) {
        int c = col[e];
        int p = atomicAdd(&cursor[c], 1);
        prow[p] = row[e];
    }
}

// ---------------- fused fc + conv1 transform --------------------------------
// md1[r] = ((x[r] @ fc_w + fc_b) @ W1) * dinv[r]
// 64-row x 64-col tile per block, 256 threads, 4x4 outputs per thread.
// h tile lives only in LDS — never touches global memory.

__global__ __launch_bounds__(256) void k_fc_mm1(const float* __restrict__ x,
        const float* __restrict__ wfc, const float* __restrict__ bfc,
        const float* __restrict__ w1, const float* __restrict__ dinv,
        float* __restrict__ md) {
    __shared__ float sfc[IND * HID];   // 32 KB  [k][c], pitch 64
    __shared__ float sw1[HID * HID];   // 16 KB  [k][c], pitch 64
    __shared__ float sx[64][33];       // 8.4 KB x-chunk [r][k], pitch 33 (conflict-free)
    __shared__ float sh[64][68];       // 17.4 KB h tile [r][c], pitch 68 (f4-aligned, 2-way)

    for (int i = threadIdx.x; i < IND * HID; i += 256) sfc[i] = wfc[i];
    for (int i = threadIdx.x; i < HID * HID; i += 256) sw1[i] = w1[i];

    const int tx = threadIdx.x;
    const int tc = tx & 15, tr = tx >> 4;
    const int c0 = tc * 4, r0 = tr * 4;
    const int rbase = blockIdx.x * 64;

    float acc[4][4];
    #pragma unroll
    for (int i = 0; i < 4; ++i) {
        #pragma unroll
        for (int j = 0; j < 4; ++j) acc[i][j] = bfc[c0 + j];
    }

    // GEMM1: h = x @ fc_w + b   (K = 128, 4 chunks of 32)
    for (int kc = 0; kc < 4; ++kc) {
        __syncthreads();   // protect previous chunk (and weight staging on iter 0)
        #pragma unroll
        for (int p = 0; p < 8; ++p) {
            int r = p * 8 + (tx >> 5);
            int k = tx & 31;
            int rg = rbase + r;
            sx[r][k] = (rg < NN) ? x[rg * IND + kc * 32 + k] : 0.f;
        }
        __syncthreads();
        #pragma unroll
        for (int k = 0; k < 32; ++k) {
            float a0 = sx[r0][k], a1 = sx[r0 + 1][k], a2 = sx[r0 + 2][k], a3 = sx[r0 + 3][k];
            float4 bv = *(const float4*)&sfc[(kc * 32 + k) * HID + c0];
            acc[0][0] += a0 * bv.x; acc[0][1] += a0 * bv.y; acc[0][2] += a0 * bv.z; acc[0][3] += a0 * bv.w;
            acc[1][0] += a1 * bv.x; acc[1][1] += a1 * bv.y; acc[1][2] += a1 * bv.z; acc[1][3] += a1 * bv.w;
            acc[2][0] += a2 * bv.x; acc[2][1] += a2 * bv.y; acc[2][2] += a2 * bv.z; acc[2][3] += a2 * bv.w;
            acc[3][0] += a3 * bv.x; acc[3][1] += a3 * bv.y; acc[3][2] += a3 * bv.z; acc[3][3] += a3 * bv.w;
        }
    }

    // h tile -> LDS (no bias/relu on fc output beyond bias already added)
    __syncthreads();
    #pragma unroll
    for (int i = 0; i < 4; ++i)
        *(float4*)&sh[r0 + i][c0] = make_float4(acc[i][0], acc[i][1], acc[i][2], acc[i][3]);
    __syncthreads();

    // GEMM2: md = (h @ W1) * dinv   (K = 64)
    float bcc[4][4] = {};
    #pragma unroll
    for (int k = 0; k < 64; ++k) {
        float a0 = sh[r0][k], a1 = sh[r0 + 1][k], a2 = sh[r0 + 2][k], a3 = sh[r0 + 3][k];
        float4 bv = *(const float4*)&sw1[k * HID + c0];
        bcc[0][0] += a0 * bv.x; bcc[0][1] += a0 * bv.y; bcc[0][2] += a0 * bv.z; bcc[0][3] += a0 * bv.w;
        bcc[1][0] += a1 * bv.x; bcc[1][1] += a1 * bv.y; bcc[1][2] += a1 * bv.z; bcc[1][3] += a1 * bv.w;
        bcc[2][0] += a2 * bv.x; bcc[2][1] += a2 * bv.y; bcc[2][2] += a2 * bv.z; bcc[2][3] += a2 * bv.w;
        bcc[3][0] += a3 * bv.x; bcc[3][1] += a3 * bv.y; bcc[3][2] += a3 * bv.z; bcc[3][3] += a3 * bv.w;
    }

    #pragma unroll
    for (int i = 0; i < 4; ++i) {
        int rg = rbase + r0 + i;
        if (rg < NN) {
            float di = dinv[rg];
            *(float4*)&md[rg * HID + c0] =
                make_float4(bcc[i][0] * di, bcc[i][1] * di, bcc[i][2] * di, bcc[i][3] * di);
        }
    }
}

// ---------------- conv2 transform: md2 = (h1 @ W2) * dinv -------------------

__global__ __launch_bounds__(256) void k_mm2(const float* __restrict__ h,
        const float* __restrict__ w, const float* __restrict__ dinv,
        float* __restrict__ md) {
    __shared__ float sw[HID * HID];    // 16 KB
    __shared__ float sh[64][65];       // 16.6 KB, pitch 65 (conflict-free scalar reads)

    for (int i = threadIdx.x; i < HID * HID; i += 256) sw[i] = w[i];

    const int tx = threadIdx.x;
    const int tc = tx & 15, tr = tx >> 4;
    const int c0 = tc * 4, r0 = tr * 4;
    const int rbase = blockIdx.x * 64;

    #pragma unroll
    for (int p = 0; p < 16; ++p) {
        int r = p * 4 + (tx >> 6);
        int k = tx & 63;
        int rg = rbase + r;
        sh[r][k] = (rg < NN) ? h[rg * HID + k] : 0.f;
    }
    __syncthreads();

    float acc[4][4] = {};
    #pragma unroll
    for (int k = 0; k < 64; ++k) {
        float a0 = sh[r0][k], a1 = sh[r0 + 1][k], a2 = sh[r0 + 2][k], a3 = sh[r0 + 3][k];
        float4 bv = *(const float4*)&sw[k * HID + c0];
        acc[0][0] += a0 * bv.x; acc[0][1] += a0 * bv.y; acc[0][2] += a0 * bv.z; acc[0][3] += a0 * bv.w;
        acc[1][0] += a1 * bv.x; acc[1][1] += a1 * bv.y; acc[1][2] += a1 * bv.z; acc[1][3] += a1 * bv.w;
        acc[2][0] += a2 * bv.x; acc[2][1] += a2 * bv.y; acc[2][2] += a2 * bv.z; acc[2][3] += a2 * bv.w;
        acc[3][0] += a3 * bv.x; acc[3][1] += a3 * bv.y; acc[3][2] += a3 * bv.z; acc[3][3] += a3 * bv.w;
    }

    #pragma unroll
    for (int i = 0; i < 4; ++i) {
        int rg = rbase + r0 + i;
        if (rg < NN) {
            float di = dinv[rg];
            *(float4*)&md[rg * HID + c0] =
                make_float4(acc[i][0] * di, acc[i][1] * di, acc[i][2] * di, acc[i][3] * di);
        }
    }
}

// ---------------- gather conv1: h1 = relu(dinv*(self + sum md[r]) + b) ------

__global__ __launch_bounds__(256) void k_gather(const float* __restrict__ md, const int* __restrict__ prow,
                                                const int* __restrict__ base, const int* __restrict__ cnt,
                                                const float* __restrict__ dinv, const float* __restrict__ b,
                                                float* __restrict__ hout) {
    int lane = threadIdx.x & 63;
    int wid  = (blockIdx.x * blockDim.x + threadIdx.x) >> 6;
    int nwv  = (gridDim.x * blockDim.x) >> 6;
    float bj = b[lane];
    for (int i = wid; i < NN; i += nwv) {
        int s = base[i], n = cnt[i];
        float acc = md[i * HID + lane];
        int e = 0;
        for (; e + 4 <= n; e += 4) {
            int r0 = prow[s + e],     r1 = prow[s + e + 1];
            int r2 = prow[s + e + 2], r3 = prow[s + e + 3];
            float v0 = md[r0 * HID + lane], v1 = md[r1 * HID + lane];
            float v2 = md[r2 * HID + lane], v3 = md[r3 * HID + lane];
            acc += (v0 + v1) + (v2 + v3);
        }
        for (; e < n; ++e) acc += md[prow[s + e] * HID + lane];
        float v = dinv[i] * acc + bj;
        hout[i * HID + lane] = v > 0.f ? v : 0.f;
    }
}

// ---------------- gather conv2 fused with scores ----------------------------
// h2 never materialized: reduce to node_score / ssrc / sdst immediately.

__global__ __launch_bounds__(256) void k_gather2s(const float* __restrict__ md, const int* __restrict__ prow,
        const int* __restrict__ base, const int* __restrict__ cnt, const float* __restrict__ dinv,
        const float* __restrict__ b, const float* __restrict__ nw, const float* __restrict__ nb,
        const float* __restrict__ ew, float* __restrict__ out_node,
        float* __restrict__ ssrc, float* __restrict__ sdst) {
    int lane = threadIdx.x & 63;
    int wid  = (blockIdx.x * blockDim.x + threadIdx.x) >> 6;
    int nwv  = (gridDim.x * blockDim.x) >> 6;
    float bj = b[lane];
    float w0 = nw[lane], w1 = ew[lane], w2 = ew[64 + lane];
    float nb0 = nb[0];
    for (int i = wid; i < NN; i += nwv) {
        int s = base[i], n = cnt[i];
        float acc = md[i * HID + lane];
        int e = 0;
        for (; e + 4 <= n; e += 4) {
            int r0 = prow[s + e],     r1 = prow[s + e + 1];
            int r2 = prow[s + e + 2], r3 = prow[s + e + 3];
            float v0 = md[r0 * HID + lane], v1 = md[r1 * HID + lane];
            float v2 = md[r2 * HID + lane], v3 = md[r3 * HID + lane];
            acc += (v0 + v1) + (v2 + v3);
        }
        for (; e < n; ++e) acc += md[prow[s + e] * HID + lane];
        float v = dinv[i] * acc + bj;
        v = v > 0.f ? v : 0.f;                 // h2 value for this (node, feature)
        float a = v * w0, s1 = v * w1, s2 = v * w2;
        #pragma unroll
        for (int off = 32; off; off >>= 1) {
            a  += __shfl_xor(a,  off, 64);
            s1 += __shfl_xor(s1, off, 64);
            s2 += __shfl_xor(s2, off, 64);
        }
        if (lane == 0) {
            out_node[i] = 1.f / (1.f + expf(-(a + nb0)));
            ssrc[i] = s1;
            sdst[i] = s2;
        }
    }
}

// ---------------- edge scores ----------------

__global__ __launch_bounds__(256) void k_edge(const int* __restrict__ row, const int* __restrict__ col,
                                              const float* __restrict__ ssrc, const float* __restrict__ sdst,
                                              const float* __restrict__ eb, float* __restrict__ out_edge) {
    int stride = gridDim.x * 256;
    float eb0 = eb[0];
    for (int i = blockIdx.x * 256 + threadIdx.x; i < EE; i += stride) {
        float z = ssrc[row[i]] + sdst[col[i]] + eb0;
        out_edge[i] = 1.f / (1.f + expf(-z));
    }
}

extern "C" void kernel_launch(void* const* d_in, const int* in_sizes, int n_in,
                              void* d_out, int out_size, void* d_ws, size_t ws_size,
                              hipStream_t stream) {
    const float* x    = (const float*)d_in[0];
    const int*   ei   = (const int*)d_in[1];
    const float* fc_w = (const float*)d_in[2];
    const float* fc_b = (const float*)d_in[3];
    const float* c1w  = (const float*)d_in[4];
    const float* c1b  = (const float*)d_in[5];
    const float* c2w  = (const float*)d_in[6];
    const float* c2b  = (const float*)d_in[7];
    const float* nw   = (const float*)d_in[8];
    const float* nb   = (const float*)d_in[9];
    const float* ew   = (const float*)d_in[10];
    const float* eb   = (const float*)d_in[11];
    const int* row = ei;        // edge_index[0]
    const int* col = ei + EE;   // edge_index[1]

    // workspace layout
    constexpr int NP = 102400;
    float* ws     = (float*)d_ws;
    float* dinv   = ws;
    float* ssrc   = ws + NP;
    float* sdst   = ws + 2 * NP;
    int*   cnt    = (int*)(ws + 3 * NP);
    int*   base   = (int*)(ws + 4 * NP);
    int*   cursor = (int*)(ws + 5 * NP);
    int*   bsum   = (int*)(ws + 6 * NP);          // 512 ints
    int*   prow   = (int*)(ws + 6 * NP + 512);    // EE ints
    float* A      = ws + 6 * NP + 512 + EE;       // h1  [N*HID]
    float* B      = A + (size_t)NN * HID;         // md  [N*HID]

    float* out_edge = (float*)d_out;
    float* out_node = out_edge + EE;

    const int nbN = (NN + 255) / 256;   // 391
    const int nbE = (EE + 255) / 256;   // 6250
    const int nbT = (NN + 63) / 64;     // 1563 GEMM tiles

    // ---- CSR build (by col) + degree norm ----
    k_zero    <<<nbN, 256, 0, stream>>>(cnt, NN);
    k_hist    <<<nbE, 256, 0, stream>>>(col, cnt);
    k_scanA   <<<NB_SCAN, 256, 0, stream>>>(cnt, base, bsum);
    k_scanB   <<<1, 512, 0, stream>>>(bsum);
    k_finalize<<<NB_SCAN, 256, 0, stream>>>(base, bsum, cnt, cursor, dinv);
    k_permute <<<nbE, 256, 0, stream>>>(row, col, cursor, prow);

    // ---- fc + conv1 transform (fused), conv1 gather ----
    k_fc_mm1<<<nbT, 256, 0, stream>>>(x, fc_w, fc_b, c1w, dinv, B);
    k_gather<<<2048, 256, 0, stream>>>(B, prow, base, cnt, dinv, c1b, A);

    // ---- conv2 transform + gather fused with scores ----
    k_mm2     <<<nbT, 256, 0, stream>>>(A, c2w, dinv, B);
    k_gather2s<<<2048, 256, 0, stream>>>(B, prow, base, cnt, dinv, c2b,
                                         nw, nb, ew, out_node, ssrc, sdst);

    // ---- edge scores ----
    k_edge<<<2048, 256, 0, stream>>>(row, col, ssrc, sdst, eb, out_edge);
}